// Round 1
// baseline (6189.988 us; speedup 1.0000x reference)
//
#include <hip/hip_runtime.h>
#include <math.h>

#define N_NODES 100000
#define NE      1600000
#define T_STEPS 8

__device__ __forceinline__ float sigmoid_f(float x) { return 1.f / (1.f + __expf(-x)); }
__device__ __forceinline__ float tanh_f(float x) {
  float e = __expf(2.f * x);
  return 1.f - 2.f / (e + 1.f);
}

// ---------------- per-snapshot CSR build ----------------
// pk[d] packs: bits 63..40 = incoming-edge count, bits 39..0 = sum(w)*2^24 fixed point.
// One 64-bit atomic per edge instead of two 32-bit atomics (halves k_hist atomic traffic).
// Quantization: each w rounded to 2^-24 absolute -> deg error ~1e-7, dinv rel err ~5e-8.

__global__ void k_init(unsigned long long* __restrict__ pk) {
  int i = blockIdx.x * 256 + threadIdx.x;
  if (i < N_NODES) pk[i] = 0ULL;
}

__global__ void k_hist(const int* __restrict__ dst, const float* __restrict__ ew,
                       unsigned long long* __restrict__ pk) {
  int e = blockIdx.x * 256 + threadIdx.x;
  if (e < NE) {
    unsigned q = __float2uint_rn(ew[e] * 16777216.0f);
    atomicAdd(&pk[dst[e]], (1ULL << 40) | (unsigned long long)q);
  }
}

// chunk = 2048 per block (256 thr x 8). Writes per-chunk exclusive scan, chunk totals to sums.
__global__ void k_scan_a(const unsigned long long* __restrict__ pk, int* __restrict__ rp,
                         int* __restrict__ sums) {
  __shared__ int sdata[256];
  int tid = threadIdx.x;
  int base = blockIdx.x * 2048 + tid * 8;
  int v[8];
  int tot = 0;
#pragma unroll
  for (int i = 0; i < 8; ++i) {
    int idx = base + i;
    int c = (idx < N_NODES) ? (int)(pk[idx] >> 40) : 0;
    v[i] = tot; tot += c;
  }
  sdata[tid] = tot;
  __syncthreads();
  for (int off = 1; off < 256; off <<= 1) {
    int x = (tid >= off) ? sdata[tid - off] : 0;
    __syncthreads();
    sdata[tid] += x;
    __syncthreads();
  }
  int texcl = sdata[tid] - tot;  // exclusive prefix of this thread within chunk
  if (tid == 255) sums[blockIdx.x] = sdata[255];
#pragma unroll
  for (int i = 0; i < 8; ++i) {
    int idx = base + i;
    if (idx < N_NODES) rp[idx] = texcl + v[i];
  }
}

// add chunk bases, fill cursor, decode deg and finalize dinv = rsqrt(1 + sum_w).
__global__ void k_scan_c(int* __restrict__ rp, const int* __restrict__ sums, int* __restrict__ cur,
                         const unsigned long long* __restrict__ pk, float* __restrict__ degv) {
  __shared__ int sbase;
  int tid = threadIdx.x;
  int cid = blockIdx.x >> 3;  // 256-thread block sits inside one 2048 chunk
  if (tid == 0) {
    int b = 0;
    for (int c = 0; c < cid; ++c) b += sums[c];
    sbase = b;
  }
  __syncthreads();
  int idx = blockIdx.x * 256 + tid;
  if (idx < N_NODES) {
    int vv = rp[idx] + sbase;
    rp[idx] = vv;
    cur[idx] = vv;
    float deg = 1.0f + (float)(pk[idx] & 0xFFFFFFFFFFULL) * 5.9604644775390625e-08f;  // 2^-24
    degv[idx] = rsqrtf(deg);
  }
  if (blockIdx.x == 0 && tid == 0) rp[N_NODES] = NE;
}

// pairs[p] = {src, bits(norm_w)}: ONE 8B scattered store per edge (was 2x 4B to two arrays).
__global__ void k_place(const int* __restrict__ src, const int* __restrict__ dst,
                        const float* __restrict__ ew, const float* __restrict__ dinv,
                        int* __restrict__ cur, int2* __restrict__ pairs) {
  int e = blockIdx.x * 256 + threadIdx.x;
  if (e < NE) {
    int s = src[e], d = dst[e];
    float w = ew[e];
    int p = atomicAdd(&cur[d], 1);
    pairs[p] = make_int2(s, __float_as_int(dinv[s] * w * dinv[d]));
  }
}

// ---------------- GCN propagation: one wave per node, lane = feature ----------------
// node wrapped in readfirstlane -> compiler can prove wave-uniformity and issue rp/pair
// loads on the scalar pipe (s_load), freeing VMEM + VALU for the hin row gathers.

__global__ void k_prop(const float* __restrict__ hin, const int* __restrict__ rp,
                       const int2* __restrict__ pairs, const float* __restrict__ dinv,
                       const float* __restrict__ bias, float* __restrict__ hout,
                       int mode /*0=relu, 1=tanh*/) {
  int node = __builtin_amdgcn_readfirstlane(blockIdx.x * 4 + (threadIdx.x >> 6));
  int f = threadIdx.x & 63;
  float di = dinv[node];
  float acc = hin[(size_t)node * 64 + f] * di * di + bias[f];  // self loop: norm = dinv^2
  int e0 = rp[node], e1 = rp[node + 1];
  float a0 = 0.f, a1 = 0.f, a2 = 0.f, a3 = 0.f;
  int j = e0;
  for (; j + 4 <= e1; j += 4) {
    int2 p0 = pairs[j], p1 = pairs[j + 1], p2 = pairs[j + 2], p3 = pairs[j + 3];
    a0 = fmaf(hin[(size_t)p0.x * 64 + f], __int_as_float(p0.y), a0);
    a1 = fmaf(hin[(size_t)p1.x * 64 + f], __int_as_float(p1.y), a1);
    a2 = fmaf(hin[(size_t)p2.x * 64 + f], __int_as_float(p2.y), a2);
    a3 = fmaf(hin[(size_t)p3.x * 64 + f], __int_as_float(p3.y), a3);
  }
  for (; j < e1; ++j) {
    int2 p = pairs[j];
    acc = fmaf(hin[(size_t)p.x * 64 + f], __int_as_float(p.y), acc);
  }
  acc += (a0 + a1) + (a2 + a3);
  hout[(size_t)node * 64 + f] = (mode == 0) ? fmaxf(acc, 0.f) : tanh_f(acc);
}

// ---------------- dense matmuls ----------------

// xw1 = x @ W1 : [N,128]@[128,64]
__global__ void k_xw1(const float* __restrict__ x, const float* __restrict__ W1, float* __restrict__ o) {
  __shared__ float sW[128 * 64];   // 32 KB
  __shared__ float sx[32 * 128];   // 16 KB
  int tid = threadIdx.x;
  int row0 = blockIdx.x * 32;
  for (int i = tid; i < 128 * 64; i += 256) sW[i] = W1[i];
  for (int i = tid; i < 32 * 128; i += 256) {
    int r = i >> 7, c = i & 127;
    sx[i] = x[(size_t)(row0 + r) * 128 + c];
  }
  __syncthreads();
  int f = tid & 63, w = tid >> 6;
  float acc[8];
#pragma unroll
  for (int m = 0; m < 8; ++m) acc[m] = 0.f;
  for (int k = 0; k < 128; ++k) {
    float wv = sW[k * 64 + f];
#pragma unroll
    for (int m = 0; m < 8; ++m)
      acc[m] = fmaf(sx[(w * 8 + m) * 128 + k], wv, acc[m]);
  }
#pragma unroll
  for (int m = 0; m < 8; ++m)
    o[(size_t)(row0 + w * 8 + m) * 64 + f] = acc[m];
}

// a = a @ W2 in place : [N,64]@[64,64] (rows staged to LDS first, so in-place is safe)
__global__ void k_mm64(float* __restrict__ a, const float* __restrict__ W2) {
  __shared__ float sW[64 * 64];   // 16 KB
  __shared__ float sx[32 * 64];   // 8 KB
  int tid = threadIdx.x;
  int row0 = blockIdx.x * 32;
  for (int i = tid; i < 64 * 64; i += 256) sW[i] = W2[i];
  for (int i = tid; i < 32 * 64; i += 256) {
    int r = i >> 6, c = i & 63;
    sx[i] = a[(size_t)(row0 + r) * 64 + c];
  }
  __syncthreads();
  int f = tid & 63, w = tid >> 6;
  float acc[8];
#pragma unroll
  for (int m = 0; m < 8; ++m) acc[m] = 0.f;
  for (int k = 0; k < 64; ++k) {
    float wv = sW[k * 64 + f];
#pragma unroll
    for (int m = 0; m < 8; ++m)
      acc[m] = fmaf(sx[(w * 8 + m) * 64 + k], wv, acc[m]);
  }
#pragma unroll
  for (int m = 0; m < 8; ++m)
    a[(size_t)(row0 + w * 8 + m) * 64 + f] = acc[m];
}

// ---------------- one-time weight prepack ----------------
// Pih/Phh[k][f*4+g] = W[(g*64+f)][k] (g<3; slot 3 = pad). Moves the gate-interleave
// transpose OUT of k_gru: staging becomes a straight coalesced, conflict-free copy.
__global__ void k_prep(const float* __restrict__ Wih, const float* __restrict__ Whh,
                       const float* __restrict__ Wlin, float* __restrict__ Pih,
                       float* __restrict__ Phh, float* __restrict__ WlinT) {
  int i = blockIdx.x * 256 + threadIdx.x;   // i < 16384
  int k = i >> 8, c = i & 255, f = c >> 2, g = c & 3;
  float vi = 0.f, vh = 0.f;
  if (g < 3) {
    vi = Wih[(size_t)(g * 64 + f) * 64 + k];
    vh = Whh[(size_t)(g * 64 + f) * 64 + k];
  }
  Pih[i] = vi;
  Phh[i] = vh;
  if (i < 2048) {
    int kk = i >> 5, j = i & 31;
    WlinT[i] = Wlin[(size_t)j * 64 + kk];
  }
}

// ---------------- fused GRU step + output linear ----------------
// 256 threads = 4 waves, 8 nodes/wave, 32 nodes/block (100000 = 32*3125 exactly).
// Round-3: weights pre-packed in global (k_prep), so staging is a linear float4 copy:
//  - writes: consecutive lanes -> consecutive LDS words -> conflict-free (was 8-way, 7.2M cyc)
//  - reads:  f*4 stride-16B ds_read_b128 = full-BW pattern, conflict-free
//  - LDS = 4*8192 = 32768 B exactly -> 5 blocks/CU (was 33280 -> 4)
__global__ __launch_bounds__(256, 5) void k_gru(
    const float* __restrict__ gt, float* __restrict__ h,
    const float* __restrict__ Pih, const float* __restrict__ Phh,
    const float* __restrict__ bih, const float* __restrict__ bhh,
    const float* __restrict__ WlinT, const float* __restrict__ blin,
    float* __restrict__ outt, int first) {
  __shared__ float sWi[8 * 256];    // 8 KB (k-tile of packed Wih)
  __shared__ float sWh[8 * 256];    // 8 KB
  __shared__ float sx[32 * 64];     // 8 KB
  __shared__ float sh[32 * 64];     // 8 KB
  // total 32768 B -> 5 blocks/CU

  int tid = threadIdx.x;
  int node0 = blockIdx.x * 32;

  {
    const float4* gx = (const float4*)(gt + (size_t)node0 * 64);
    float4* lx = (float4*)sx;
    float4* lh = (float4*)sh;
    lx[tid] = gx[tid];
    lx[tid + 256] = gx[tid + 256];
    if (first) {
      float4 z4 = make_float4(0.f, 0.f, 0.f, 0.f);
      lh[tid] = z4;
      lh[tid + 256] = z4;
    } else {
      const float4* gh = (const float4*)(h + (size_t)node0 * 64);
      lh[tid] = gh[tid];
      lh[tid + 256] = gh[tid + 256];
    }
  }

  int f = tid & 63;
  int w = tid >> 6;   // 0..3
  int mb = w * 8;

  float air[8], aiz[8], ain[8], ahr[8], ahz[8], ahn[8];
#pragma unroll
  for (int m = 0; m < 8; ++m) { air[m]=0.f; aiz[m]=0.f; ain[m]=0.f; ahr[m]=0.f; ahz[m]=0.f; ahn[m]=0.f; }

  for (int kt = 0; kt < 64; kt += 8) {
    __syncthreads();  // prior tile reads done (also covers initial sx/sh staging)
    {  // stage k-tile: 512 float4 per buffer, linear copy, conflict-free
      const float4* gi = (const float4*)(Pih + (size_t)kt * 256);
      const float4* gh4 = (const float4*)(Phh + (size_t)kt * 256);
      float4* li = (float4*)sWi;
      float4* lh4 = (float4*)sWh;
      li[tid] = gi[tid];
      li[tid + 256] = gi[tid + 256];
      lh4[tid] = gh4[tid];
      lh4[tid + 256] = gh4[tid + 256];
    }
    __syncthreads();
#pragma unroll
    for (int kg = 0; kg < 8; kg += 4) {
      float4 wi0 = *reinterpret_cast<const float4*>(&sWi[(kg + 0) * 256 + f * 4]);
      float4 wi1 = *reinterpret_cast<const float4*>(&sWi[(kg + 1) * 256 + f * 4]);
      float4 wi2 = *reinterpret_cast<const float4*>(&sWi[(kg + 2) * 256 + f * 4]);
      float4 wi3 = *reinterpret_cast<const float4*>(&sWi[(kg + 3) * 256 + f * 4]);
      float4 wh0 = *reinterpret_cast<const float4*>(&sWh[(kg + 0) * 256 + f * 4]);
      float4 wh1 = *reinterpret_cast<const float4*>(&sWh[(kg + 1) * 256 + f * 4]);
      float4 wh2 = *reinterpret_cast<const float4*>(&sWh[(kg + 2) * 256 + f * 4]);
      float4 wh3 = *reinterpret_cast<const float4*>(&sWh[(kg + 3) * 256 + f * 4]);
#pragma unroll
      for (int m = 0; m < 8; ++m) {
        float4 xm = *reinterpret_cast<const float4*>(&sx[(mb + m) * 64 + kt + kg]);  // broadcast
        float4 hm = *reinterpret_cast<const float4*>(&sh[(mb + m) * 64 + kt + kg]);  // broadcast
        air[m] = fmaf(xm.x, wi0.x, air[m]); aiz[m] = fmaf(xm.x, wi0.y, aiz[m]); ain[m] = fmaf(xm.x, wi0.z, ain[m]);
        ahr[m] = fmaf(hm.x, wh0.x, ahr[m]); ahz[m] = fmaf(hm.x, wh0.y, ahz[m]); ahn[m] = fmaf(hm.x, wh0.z, ahn[m]);
        air[m] = fmaf(xm.y, wi1.x, air[m]); aiz[m] = fmaf(xm.y, wi1.y, aiz[m]); ain[m] = fmaf(xm.y, wi1.z, ain[m]);
        ahr[m] = fmaf(hm.y, wh1.x, ahr[m]); ahz[m] = fmaf(hm.y, wh1.y, ahz[m]); ahn[m] = fmaf(hm.y, wh1.z, ahn[m]);
        air[m] = fmaf(xm.z, wi2.x, air[m]); aiz[m] = fmaf(xm.z, wi2.y, aiz[m]); ain[m] = fmaf(xm.z, wi2.z, ain[m]);
        ahr[m] = fmaf(hm.z, wh2.x, ahr[m]); ahz[m] = fmaf(hm.z, wh2.y, ahz[m]); ahn[m] = fmaf(hm.z, wh2.z, ahn[m]);
        air[m] = fmaf(xm.w, wi3.x, air[m]); aiz[m] = fmaf(xm.w, wi3.y, aiz[m]); ain[m] = fmaf(xm.w, wi3.z, ain[m]);
        ahr[m] = fmaf(hm.w, wh3.x, ahr[m]); ahz[m] = fmaf(hm.w, wh3.y, ahz[m]); ahn[m] = fmaf(hm.w, wh3.z, ahn[m]);
      }
    }
  }

  float bir = bih[f], biz = bih[64 + f], bin = bih[128 + f];
  float bhr = bhh[f], bhz = bhh[64 + f], bhn = bhh[128 + f];

  float hnew[8];
#pragma unroll
  for (int m = 0; m < 8; ++m) {
    float r = sigmoid_f(air[m] + bir + ahr[m] + bhr);
    float z = sigmoid_f(aiz[m] + biz + ahz[m] + bhz);
    float nn = tanh_f(ain[m] + bin + r * (ahn[m] + bhn));
    float hold = sh[(mb + m) * 64 + f];  // own-wave row, safe
    hnew[m] = (1.f - z) * nn + z * hold;
  }
#pragma unroll
  for (int m = 0; m < 8; ++m) {
    sh[(mb + m) * 64 + f] = hnew[m];  // own-wave rows only; no cross-wave hazard
    h[(size_t)(node0 + mb + m) * 64 + f] = hnew[m];
  }

  __syncthreads();  // all waves done reading sWi before reuse for WlinT
  for (int i = tid; i < 2048; i += 256) sWi[i] = WlinT[i];
  __syncthreads();

  int j = f & 31, hi = f >> 5;
  float o0 = blin[j], o1 = o0, o2 = o0, o3 = o0;
  for (int k = 0; k < 64; ++k) {
    float wv = sWi[k * 32 + j];
    o0 = fmaf(sh[(mb + 0 + hi) * 64 + k], wv, o0);
    o1 = fmaf(sh[(mb + 2 + hi) * 64 + k], wv, o1);
    o2 = fmaf(sh[(mb + 4 + hi) * 64 + k], wv, o2);
    o3 = fmaf(sh[(mb + 6 + hi) * 64 + k], wv, o3);
  }
  outt[(size_t)(node0 + mb + 0 + hi) * 32 + j] = o0;
  outt[(size_t)(node0 + mb + 2 + hi) * 32 + j] = o1;
  outt[(size_t)(node0 + mb + 4 + hi) * 32 + j] = o2;
  outt[(size_t)(node0 + mb + 6 + hi) * 32 + j] = o3;
}

// ---------------- host launch ----------------

extern "C" void kernel_launch(void* const* d_in, const int* in_sizes, int n_in,
                              void* d_out, int out_size, void* d_ws, size_t ws_size,
                              hipStream_t stream) {
  const float* x    = (const float*)d_in[0];
  const int*   eis  = (const int*)d_in[1];
  const float* ews  = (const float*)d_in[2];
  const float* W1   = (const float*)d_in[3];
  const float* b1   = (const float*)d_in[4];
  const float* W2   = (const float*)d_in[5];
  const float* b2   = (const float*)d_in[6];
  const float* Wih  = (const float*)d_in[7];
  const float* Whh  = (const float*)d_in[8];
  const float* bih  = (const float*)d_in[9];
  const float* bhh  = (const float*)d_in[10];
  const float* Wlin = (const float*)d_in[11];
  const float* blin = (const float*)d_in[12];
  float* out = (float*)d_out;

  char* ws = (char*)d_ws;
  size_t off = 0;
  auto alloc = [&](size_t bytes) { char* p = ws + off; off += (bytes + 255) & ~size_t(255); return p; };
  float* xw1  = (float*)alloc((size_t)N_NODES * 64 * 4);
  float* bufA = (float*)alloc((size_t)N_NODES * 64 * 4);  // h1, then h2 in place
  float* bufB = (float*)alloc((size_t)N_NODES * 64 * 4);  // tanh(embed_t)
  float* hst  = (float*)alloc((size_t)N_NODES * 64 * 4);  // GRU hidden state
  float* degv = (float*)alloc((size_t)N_NODES * 4);       // dinv
  unsigned long long* pk = (unsigned long long*)alloc((size_t)N_NODES * 8);
  int*   rp   = (int*)alloc((size_t)(N_NODES + 1) * 4);
  int*   cur  = (int*)alloc((size_t)(N_NODES + 1) * 4);
  int*   sums = (int*)alloc(64 * 4);
  int2*  pairs = (int2*)alloc((size_t)NE * 8);
  float* Pih  = (float*)alloc(64 * 256 * 4);
  float* Phh  = (float*)alloc(64 * 256 * 4);
  float* WlinT = (float*)alloc(64 * 32 * 4);
  if (ws_size < off) return;  // workspace too small: fail loudly in validation

  const int GB_N   = (N_NODES + 255) / 256;   // 391
  const int GB_E   = (NE + 255) / 256;        // 6250
  const int GB_SC  = (N_NODES + 2047) / 2048; // 49
  const int GB_MM  = N_NODES / 32;            // 3125
  const int GB_PR  = N_NODES / 4;             // 25000
  const int GB_GRU = N_NODES / 32;            // 3125

  k_prep<<<64, 256, 0, stream>>>(Wih, Whh, Wlin, Pih, Phh, WlinT);
  k_xw1<<<GB_MM, 256, 0, stream>>>(x, W1, xw1);

  for (int t = 0; t < T_STEPS; ++t) {
    const int* srcp = eis + (size_t)t * 2 * NE;
    const int* dstp = srcp + NE;
    const float* ewp = ews + (size_t)t * NE;

    k_init<<<GB_N, 256, 0, stream>>>(pk);
    k_hist<<<GB_E, 256, 0, stream>>>(dstp, ewp, pk);
    k_scan_a<<<GB_SC, 256, 0, stream>>>(pk, rp, sums);
    k_scan_c<<<GB_N, 256, 0, stream>>>(rp, sums, cur, pk, degv);
    k_place<<<GB_E, 256, 0, stream>>>(srcp, dstp, ewp, degv, cur, pairs);

    // layer 1: relu(prop(xw1) + b1) -> bufA
    k_prop<<<GB_PR, 256, 0, stream>>>(xw1, rp, pairs, degv, b1, bufA, 0);
    // h2 = h1 @ W2 (in place)
    k_mm64<<<GB_MM, 256, 0, stream>>>(bufA, W2);
    // layer 2 + GRU input activation: tanh(prop(h2) + b2) -> bufB
    k_prop<<<GB_PR, 256, 0, stream>>>(bufA, rp, pairs, degv, b2, bufB, 1);
    // GRU step + fused output linear
    k_gru<<<GB_GRU, 256, 0, stream>>>(bufB, hst, Pih, Phh, bih, bhh, WlinT, blin,
                                      out + (size_t)t * N_NODES * 32, t == 0 ? 1 : 0);
  }
}

// Round 2
// 5145.715 us; speedup vs baseline: 1.2029x; 1.2029x over previous
//
#include <hip/hip_runtime.h>
#include <math.h>

#define N_NODES 100000
#define NE      1600000
#define T_STEPS 8

__device__ __forceinline__ float sigmoid_f(float x) { return 1.f / (1.f + __expf(-x)); }
__device__ __forceinline__ float tanh_f(float x) {
  float e = __expf(2.f * x);
  return 1.f - 2.f / (e + 1.f);
}

// ---------------- per-snapshot CSR build ----------------
// pk[d] packs: bits 63..40 = incoming-edge count, bits 39..0 = sum(w)*2^24 fixed point.
// One 64-bit atomic per edge instead of two 32-bit atomics (halves k_hist atomic traffic).
// Quantization: each w rounded to 2^-24 absolute -> deg error ~1e-7, dinv rel err ~5e-8.

__global__ void k_init(unsigned long long* __restrict__ pk) {
  int i = blockIdx.x * 256 + threadIdx.x;
  if (i < N_NODES) pk[i] = 0ULL;
}

__global__ void k_hist(const int* __restrict__ dst, const float* __restrict__ ew,
                       unsigned long long* __restrict__ pk) {
  int e = blockIdx.x * 256 + threadIdx.x;
  if (e < NE) {
    unsigned q = __float2uint_rn(ew[e] * 16777216.0f);
    atomicAdd(&pk[dst[e]], (1ULL << 40) | (unsigned long long)q);
  }
}

// chunk = 2048 per block (256 thr x 8). Writes per-chunk exclusive scan, chunk totals to sums.
__global__ void k_scan_a(const unsigned long long* __restrict__ pk, int* __restrict__ rp,
                         int* __restrict__ sums) {
  __shared__ int sdata[256];
  int tid = threadIdx.x;
  int base = blockIdx.x * 2048 + tid * 8;
  int v[8];
  int tot = 0;
#pragma unroll
  for (int i = 0; i < 8; ++i) {
    int idx = base + i;
    int c = (idx < N_NODES) ? (int)(pk[idx] >> 40) : 0;
    v[i] = tot; tot += c;
  }
  sdata[tid] = tot;
  __syncthreads();
  for (int off = 1; off < 256; off <<= 1) {
    int x = (tid >= off) ? sdata[tid - off] : 0;
    __syncthreads();
    sdata[tid] += x;
    __syncthreads();
  }
  int texcl = sdata[tid] - tot;  // exclusive prefix of this thread within chunk
  if (tid == 255) sums[blockIdx.x] = sdata[255];
#pragma unroll
  for (int i = 0; i < 8; ++i) {
    int idx = base + i;
    if (idx < N_NODES) rp[idx] = texcl + v[i];
  }
}

// add chunk bases, fill cursor, decode deg and finalize dinv = rsqrt(1 + sum_w).
__global__ void k_scan_c(int* __restrict__ rp, const int* __restrict__ sums, int* __restrict__ cur,
                         const unsigned long long* __restrict__ pk, float* __restrict__ degv) {
  __shared__ int sbase;
  int tid = threadIdx.x;
  int cid = blockIdx.x >> 3;  // 256-thread block sits inside one 2048 chunk
  if (tid == 0) {
    int b = 0;
    for (int c = 0; c < cid; ++c) b += sums[c];
    sbase = b;
  }
  __syncthreads();
  int idx = blockIdx.x * 256 + tid;
  if (idx < N_NODES) {
    int vv = rp[idx] + sbase;
    rp[idx] = vv;
    cur[idx] = vv;
    float deg = 1.0f + (float)(pk[idx] & 0xFFFFFFFFFFULL) * 5.9604644775390625e-08f;  // 2^-24
    degv[idx] = rsqrtf(deg);
  }
  if (blockIdx.x == 0 && tid == 0) rp[N_NODES] = NE;
}

// pairs[p] = {src, bits(norm_w)}: ONE 8B scattered store per edge (was 2x 4B to two arrays).
__global__ void k_place(const int* __restrict__ src, const int* __restrict__ dst,
                        const float* __restrict__ ew, const float* __restrict__ dinv,
                        int* __restrict__ cur, int2* __restrict__ pairs) {
  int e = blockIdx.x * 256 + threadIdx.x;
  if (e < NE) {
    int s = src[e], d = dst[e];
    float w = ew[e];
    int p = atomicAdd(&cur[d], 1);
    pairs[p] = make_int2(s, __float_as_int(dinv[s] * w * dinv[d]));
  }
}

// ---------------- GCN propagation: one wave per node, lane = feature ----------------
// node wrapped in readfirstlane -> compiler can prove wave-uniformity and issue rp/pair
// loads on the scalar pipe (s_load), freeing VMEM + VALU for the hin row gathers.

__global__ void k_prop(const float* __restrict__ hin, const int* __restrict__ rp,
                       const int2* __restrict__ pairs, const float* __restrict__ dinv,
                       const float* __restrict__ bias, float* __restrict__ hout,
                       int mode /*0=relu, 1=tanh*/) {
  int node = __builtin_amdgcn_readfirstlane(blockIdx.x * 4 + (threadIdx.x >> 6));
  int f = threadIdx.x & 63;
  float di = dinv[node];
  float acc = hin[(size_t)node * 64 + f] * di * di + bias[f];  // self loop: norm = dinv^2
  int e0 = rp[node], e1 = rp[node + 1];
  float a0 = 0.f, a1 = 0.f, a2 = 0.f, a3 = 0.f;
  int j = e0;
  for (; j + 4 <= e1; j += 4) {
    int2 p0 = pairs[j], p1 = pairs[j + 1], p2 = pairs[j + 2], p3 = pairs[j + 3];
    a0 = fmaf(hin[(size_t)p0.x * 64 + f], __int_as_float(p0.y), a0);
    a1 = fmaf(hin[(size_t)p1.x * 64 + f], __int_as_float(p1.y), a1);
    a2 = fmaf(hin[(size_t)p2.x * 64 + f], __int_as_float(p2.y), a2);
    a3 = fmaf(hin[(size_t)p3.x * 64 + f], __int_as_float(p3.y), a3);
  }
  for (; j < e1; ++j) {
    int2 p = pairs[j];
    acc = fmaf(hin[(size_t)p.x * 64 + f], __int_as_float(p.y), acc);
  }
  acc += (a0 + a1) + (a2 + a3);
  hout[(size_t)node * 64 + f] = (mode == 0) ? fmaxf(acc, 0.f) : tanh_f(acc);
}

// ---------------- dense matmuls ----------------

// xw1 = x @ W1 : [N,128]@[128,64]
__global__ void k_xw1(const float* __restrict__ x, const float* __restrict__ W1, float* __restrict__ o) {
  __shared__ float sW[128 * 64];   // 32 KB
  __shared__ float sx[32 * 128];   // 16 KB
  int tid = threadIdx.x;
  int row0 = blockIdx.x * 32;
  for (int i = tid; i < 128 * 64; i += 256) sW[i] = W1[i];
  for (int i = tid; i < 32 * 128; i += 256) {
    int r = i >> 7, c = i & 127;
    sx[i] = x[(size_t)(row0 + r) * 128 + c];
  }
  __syncthreads();
  int f = tid & 63, w = tid >> 6;
  float acc[8];
#pragma unroll
  for (int m = 0; m < 8; ++m) acc[m] = 0.f;
  for (int k = 0; k < 128; ++k) {
    float wv = sW[k * 64 + f];
#pragma unroll
    for (int m = 0; m < 8; ++m)
      acc[m] = fmaf(sx[(w * 8 + m) * 128 + k], wv, acc[m]);
  }
#pragma unroll
  for (int m = 0; m < 8; ++m)
    o[(size_t)(row0 + w * 8 + m) * 64 + f] = acc[m];
}

// a = a @ W2 in place : [N,64]@[64,64] (rows staged to LDS first, so in-place is safe)
__global__ void k_mm64(float* __restrict__ a, const float* __restrict__ W2) {
  __shared__ float sW[64 * 64];   // 16 KB
  __shared__ float sx[32 * 64];   // 8 KB
  int tid = threadIdx.x;
  int row0 = blockIdx.x * 32;
  for (int i = tid; i < 64 * 64; i += 256) sW[i] = W2[i];
  for (int i = tid; i < 32 * 64; i += 256) {
    int r = i >> 6, c = i & 63;
    sx[i] = a[(size_t)(row0 + r) * 64 + c];
  }
  __syncthreads();
  int f = tid & 63, w = tid >> 6;
  float acc[8];
#pragma unroll
  for (int m = 0; m < 8; ++m) acc[m] = 0.f;
  for (int k = 0; k < 64; ++k) {
    float wv = sW[k * 64 + f];
#pragma unroll
    for (int m = 0; m < 8; ++m)
      acc[m] = fmaf(sx[(w * 8 + m) * 64 + k], wv, acc[m]);
  }
#pragma unroll
  for (int m = 0; m < 8; ++m)
    a[(size_t)(row0 + w * 8 + m) * 64 + f] = acc[m];
}

// ---------------- one-time weight prepack ----------------
// Pih/Phh[k][f*4+g] = W[(g*64+f)][k] (g<3; slot 3 = pad). Moves the gate-interleave
// transpose OUT of k_gru: staging becomes a straight coalesced, conflict-free copy.
__global__ void k_prep(const float* __restrict__ Wih, const float* __restrict__ Whh,
                       const float* __restrict__ Wlin, float* __restrict__ Pih,
                       float* __restrict__ Phh, float* __restrict__ WlinT) {
  int i = blockIdx.x * 256 + threadIdx.x;   // i < 16384
  int k = i >> 8, c = i & 255, f = c >> 2, g = c & 3;
  float vi = 0.f, vh = 0.f;
  if (g < 3) {
    vi = Wih[(size_t)(g * 64 + f) * 64 + k];
    vh = Whh[(size_t)(g * 64 + f) * 64 + k];
  }
  Pih[i] = vi;
  Phh[i] = vh;
  if (i < 2048) {
    int kk = i >> 5, j = i & 31;
    WlinT[i] = Wlin[(size_t)j * 64 + kk];
  }
}

// ---------------- fused GRU step + output linear ----------------
// 256 threads = 4 waves, 8 nodes/wave, 32 nodes/block (100000 = 32*3125 exactly).
// Round-3: weights pre-packed (k_prep): staging is a linear float4 copy, conflict-free;
// reads are stride-16B ds_read_b128, conflict-free (verified: SQ_LDS_BANK_CONFLICT = 0).
// Round-4 FIX: launch_bounds(256,5) capped VGPRs at ~102 -> allocator hit 48 + scratch
// spills (WRITE_SIZE 1.24 GB/dispatch, 3x slowdown). Kernel needs ~84 VGPRs live.
// (256,4) -> cap 128 VGPRs, 4 blocks/CU (LDS 32 KB allows it), no spill.
__global__ __launch_bounds__(256, 4) void k_gru(
    const float* __restrict__ gt, float* __restrict__ h,
    const float* __restrict__ Pih, const float* __restrict__ Phh,
    const float* __restrict__ bih, const float* __restrict__ bhh,
    const float* __restrict__ WlinT, const float* __restrict__ blin,
    float* __restrict__ outt, int first) {
  __shared__ float sWi[8 * 256];    // 8 KB (k-tile of packed Wih)
  __shared__ float sWh[8 * 256];    // 8 KB
  __shared__ float sx[32 * 64];     // 8 KB
  __shared__ float sh[32 * 64];     // 8 KB
  // total 32768 B -> 4 blocks/CU with the 128-VGPR cap

  int tid = threadIdx.x;
  int node0 = blockIdx.x * 32;

  {
    const float4* gx = (const float4*)(gt + (size_t)node0 * 64);
    float4* lx = (float4*)sx;
    float4* lh = (float4*)sh;
    lx[tid] = gx[tid];
    lx[tid + 256] = gx[tid + 256];
    if (first) {
      float4 z4 = make_float4(0.f, 0.f, 0.f, 0.f);
      lh[tid] = z4;
      lh[tid + 256] = z4;
    } else {
      const float4* gh = (const float4*)(h + (size_t)node0 * 64);
      lh[tid] = gh[tid];
      lh[tid + 256] = gh[tid + 256];
    }
  }

  int f = tid & 63;
  int w = tid >> 6;   // 0..3
  int mb = w * 8;

  float air[8], aiz[8], ain[8], ahr[8], ahz[8], ahn[8];
#pragma unroll
  for (int m = 0; m < 8; ++m) { air[m]=0.f; aiz[m]=0.f; ain[m]=0.f; ahr[m]=0.f; ahz[m]=0.f; ahn[m]=0.f; }

  for (int kt = 0; kt < 64; kt += 8) {
    __syncthreads();  // prior tile reads done (also covers initial sx/sh staging)
    {  // stage k-tile: 512 float4 per buffer, linear copy, conflict-free
      const float4* gi = (const float4*)(Pih + (size_t)kt * 256);
      const float4* gh4 = (const float4*)(Phh + (size_t)kt * 256);
      float4* li = (float4*)sWi;
      float4* lh4 = (float4*)sWh;
      li[tid] = gi[tid];
      li[tid + 256] = gi[tid + 256];
      lh4[tid] = gh4[tid];
      lh4[tid + 256] = gh4[tid + 256];
    }
    __syncthreads();
#pragma unroll
    for (int kg = 0; kg < 8; kg += 4) {
      float4 wi0 = *reinterpret_cast<const float4*>(&sWi[(kg + 0) * 256 + f * 4]);
      float4 wi1 = *reinterpret_cast<const float4*>(&sWi[(kg + 1) * 256 + f * 4]);
      float4 wi2 = *reinterpret_cast<const float4*>(&sWi[(kg + 2) * 256 + f * 4]);
      float4 wi3 = *reinterpret_cast<const float4*>(&sWi[(kg + 3) * 256 + f * 4]);
      float4 wh0 = *reinterpret_cast<const float4*>(&sWh[(kg + 0) * 256 + f * 4]);
      float4 wh1 = *reinterpret_cast<const float4*>(&sWh[(kg + 1) * 256 + f * 4]);
      float4 wh2 = *reinterpret_cast<const float4*>(&sWh[(kg + 2) * 256 + f * 4]);
      float4 wh3 = *reinterpret_cast<const float4*>(&sWh[(kg + 3) * 256 + f * 4]);
#pragma unroll
      for (int m = 0; m < 8; ++m) {
        float4 xm = *reinterpret_cast<const float4*>(&sx[(mb + m) * 64 + kt + kg]);  // broadcast
        float4 hm = *reinterpret_cast<const float4*>(&sh[(mb + m) * 64 + kt + kg]);  // broadcast
        air[m] = fmaf(xm.x, wi0.x, air[m]); aiz[m] = fmaf(xm.x, wi0.y, aiz[m]); ain[m] = fmaf(xm.x, wi0.z, ain[m]);
        ahr[m] = fmaf(hm.x, wh0.x, ahr[m]); ahz[m] = fmaf(hm.x, wh0.y, ahz[m]); ahn[m] = fmaf(hm.x, wh0.z, ahn[m]);
        air[m] = fmaf(xm.y, wi1.x, air[m]); aiz[m] = fmaf(xm.y, wi1.y, aiz[m]); ain[m] = fmaf(xm.y, wi1.z, ain[m]);
        ahr[m] = fmaf(hm.y, wh1.x, ahr[m]); ahz[m] = fmaf(hm.y, wh1.y, ahz[m]); ahn[m] = fmaf(hm.y, wh1.z, ahn[m]);
        air[m] = fmaf(xm.z, wi2.x, air[m]); aiz[m] = fmaf(xm.z, wi2.y, aiz[m]); ain[m] = fmaf(xm.z, wi2.z, ain[m]);
        ahr[m] = fmaf(hm.z, wh2.x, ahr[m]); ahz[m] = fmaf(hm.z, wh2.y, ahz[m]); ahn[m] = fmaf(hm.z, wh2.z, ahn[m]);
        air[m] = fmaf(xm.w, wi3.x, air[m]); aiz[m] = fmaf(xm.w, wi3.y, aiz[m]); ain[m] = fmaf(xm.w, wi3.z, ain[m]);
        ahr[m] = fmaf(hm.w, wh3.x, ahr[m]); ahz[m] = fmaf(hm.w, wh3.y, ahz[m]); ahn[m] = fmaf(hm.w, wh3.z, ahn[m]);
      }
    }
  }

  float bir = bih[f], biz = bih[64 + f], bin = bih[128 + f];
  float bhr = bhh[f], bhz = bhh[64 + f], bhn = bhh[128 + f];

  float hnew[8];
#pragma unroll
  for (int m = 0; m < 8; ++m) {
    float r = sigmoid_f(air[m] + bir + ahr[m] + bhr);
    float z = sigmoid_f(aiz[m] + biz + ahz[m] + bhz);
    float nn = tanh_f(ain[m] + bin + r * (ahn[m] + bhn));
    float hold = sh[(mb + m) * 64 + f];  // own-wave row, safe
    hnew[m] = (1.f - z) * nn + z * hold;
  }
#pragma unroll
  for (int m = 0; m < 8; ++m) {
    sh[(mb + m) * 64 + f] = hnew[m];  // own-wave rows only; no cross-wave hazard
    h[(size_t)(node0 + mb + m) * 64 + f] = hnew[m];
  }

  __syncthreads();  // all waves done reading sWi before reuse for WlinT
  for (int i = tid; i < 2048; i += 256) sWi[i] = WlinT[i];
  __syncthreads();

  int j = f & 31, hi = f >> 5;
  float o0 = blin[j], o1 = o0, o2 = o0, o3 = o0;
  for (int k = 0; k < 64; ++k) {
    float wv = sWi[k * 32 + j];
    o0 = fmaf(sh[(mb + 0 + hi) * 64 + k], wv, o0);
    o1 = fmaf(sh[(mb + 2 + hi) * 64 + k], wv, o1);
    o2 = fmaf(sh[(mb + 4 + hi) * 64 + k], wv, o2);
    o3 = fmaf(sh[(mb + 6 + hi) * 64 + k], wv, o3);
  }
  outt[(size_t)(node0 + mb + 0 + hi) * 32 + j] = o0;
  outt[(size_t)(node0 + mb + 2 + hi) * 32 + j] = o1;
  outt[(size_t)(node0 + mb + 4 + hi) * 32 + j] = o2;
  outt[(size_t)(node0 + mb + 6 + hi) * 32 + j] = o3;
}

// ---------------- host launch ----------------

extern "C" void kernel_launch(void* const* d_in, const int* in_sizes, int n_in,
                              void* d_out, int out_size, void* d_ws, size_t ws_size,
                              hipStream_t stream) {
  const float* x    = (const float*)d_in[0];
  const int*   eis  = (const int*)d_in[1];
  const float* ews  = (const float*)d_in[2];
  const float* W1   = (const float*)d_in[3];
  const float* b1   = (const float*)d_in[4];
  const float* W2   = (const float*)d_in[5];
  const float* b2   = (const float*)d_in[6];
  const float* Wih  = (const float*)d_in[7];
  const float* Whh  = (const float*)d_in[8];
  const float* bih  = (const float*)d_in[9];
  const float* bhh  = (const float*)d_in[10];
  const float* Wlin = (const float*)d_in[11];
  const float* blin = (const float*)d_in[12];
  float* out = (float*)d_out;

  char* ws = (char*)d_ws;
  size_t off = 0;
  auto alloc = [&](size_t bytes) { char* p = ws + off; off += (bytes + 255) & ~size_t(255); return p; };
  float* xw1  = (float*)alloc((size_t)N_NODES * 64 * 4);
  float* bufA = (float*)alloc((size_t)N_NODES * 64 * 4);  // h1, then h2 in place
  float* bufB = (float*)alloc((size_t)N_NODES * 64 * 4);  // tanh(embed_t)
  float* hst  = (float*)alloc((size_t)N_NODES * 64 * 4);  // GRU hidden state
  float* degv = (float*)alloc((size_t)N_NODES * 4);       // dinv
  unsigned long long* pk = (unsigned long long*)alloc((size_t)N_NODES * 8);
  int*   rp   = (int*)alloc((size_t)(N_NODES + 1) * 4);
  int*   cur  = (int*)alloc((size_t)(N_NODES + 1) * 4);
  int*   sums = (int*)alloc(64 * 4);
  int2*  pairs = (int2*)alloc((size_t)NE * 8);
  float* Pih  = (float*)alloc(64 * 256 * 4);
  float* Phh  = (float*)alloc(64 * 256 * 4);
  float* WlinT = (float*)alloc(64 * 32 * 4);
  if (ws_size < off) return;  // workspace too small: fail loudly in validation

  const int GB_N   = (N_NODES + 255) / 256;   // 391
  const int GB_E   = (NE + 255) / 256;        // 6250
  const int GB_SC  = (N_NODES + 2047) / 2048; // 49
  const int GB_MM  = N_NODES / 32;            // 3125
  const int GB_PR  = N_NODES / 4;             // 25000
  const int GB_GRU = N_NODES / 32;            // 3125

  k_prep<<<64, 256, 0, stream>>>(Wih, Whh, Wlin, Pih, Phh, WlinT);
  k_xw1<<<GB_MM, 256, 0, stream>>>(x, W1, xw1);

  for (int t = 0; t < T_STEPS; ++t) {
    const int* srcp = eis + (size_t)t * 2 * NE;
    const int* dstp = srcp + NE;
    const float* ewp = ews + (size_t)t * NE;

    k_init<<<GB_N, 256, 0, stream>>>(pk);
    k_hist<<<GB_E, 256, 0, stream>>>(dstp, ewp, pk);
    k_scan_a<<<GB_SC, 256, 0, stream>>>(pk, rp, sums);
    k_scan_c<<<GB_N, 256, 0, stream>>>(rp, sums, cur, pk, degv);
    k_place<<<GB_E, 256, 0, stream>>>(srcp, dstp, ewp, degv, cur, pairs);

    // layer 1: relu(prop(xw1) + b1) -> bufA
    k_prop<<<GB_PR, 256, 0, stream>>>(xw1, rp, pairs, degv, b1, bufA, 0);
    // h2 = h1 @ W2 (in place)
    k_mm64<<<GB_MM, 256, 0, stream>>>(bufA, W2);
    // layer 2 + GRU input activation: tanh(prop(h2) + b2) -> bufB
    k_prop<<<GB_PR, 256, 0, stream>>>(bufA, rp, pairs, degv, b2, bufB, 1);
    // GRU step + fused output linear
    k_gru<<<GB_GRU, 256, 0, stream>>>(bufB, hst, Pih, Phh, bih, bhh, WlinT, blin,
                                      out + (size_t)t * N_NODES * 32, t == 0 ? 1 : 0);
  }
}

// Round 4
// 3636.589 us; speedup vs baseline: 1.7021x; 1.4150x over previous
//
#include <hip/hip_runtime.h>
#include <math.h>

#define N_NODES 100000
#define NE      1600000
#define T_STEPS 8

__device__ __forceinline__ float sigmoid_f(float x) { return 1.f / (1.f + __expf(-x)); }
__device__ __forceinline__ float tanh_f(float x) {
  float e = __expf(2.f * x);
  return 1.f - 2.f / (e + 1.f);
}

// ---------------- per-snapshot CSR build ----------------
// pk[d] packs: bits 63..40 = incoming-edge count, bits 39..0 = sum(w)*2^24 fixed point.
// One 64-bit atomic per edge instead of two 32-bit atomics.
// Quantization: each w rounded to 2^-24 absolute -> deg error ~1e-7, dinv rel err ~5e-8.

__global__ void k_init(unsigned long long* __restrict__ pk) {
  int i = blockIdx.x * 256 + threadIdx.x;
  if (i < N_NODES) pk[i] = 0ULL;
}

__global__ void k_hist(const int* __restrict__ dst, const float* __restrict__ ew,
                       unsigned long long* __restrict__ pk) {
  int e = blockIdx.x * 256 + threadIdx.x;
  if (e < NE) {
    unsigned q = __float2uint_rn(ew[e] * 16777216.0f);
    atomicAdd(&pk[dst[e]], (1ULL << 40) | (unsigned long long)q);
  }
}

// chunk = 2048 per block (256 thr x 8). Writes per-chunk exclusive scan, chunk totals to sums.
__global__ void k_scan_a(const unsigned long long* __restrict__ pk, int* __restrict__ rp,
                         int* __restrict__ sums) {
  __shared__ int sdata[256];
  int tid = threadIdx.x;
  int base = blockIdx.x * 2048 + tid * 8;
  int v[8];
  int tot = 0;
#pragma unroll
  for (int i = 0; i < 8; ++i) {
    int idx = base + i;
    int c = (idx < N_NODES) ? (int)(pk[idx] >> 40) : 0;
    v[i] = tot; tot += c;
  }
  sdata[tid] = tot;
  __syncthreads();
  for (int off = 1; off < 256; off <<= 1) {
    int x = (tid >= off) ? sdata[tid - off] : 0;
    __syncthreads();
    sdata[tid] += x;
    __syncthreads();
  }
  int texcl = sdata[tid] - tot;  // exclusive prefix of this thread within chunk
  if (tid == 255) sums[blockIdx.x] = sdata[255];
#pragma unroll
  for (int i = 0; i < 8; ++i) {
    int idx = base + i;
    if (idx < N_NODES) rp[idx] = texcl + v[i];
  }
}

// add chunk bases, fill cursor, decode deg -> dinv, and RE-ZERO pk for the next snapshot
// (k_init runs only once, before the t-loop; this is pk's last reader each iteration).
__global__ void k_scan_c(int* __restrict__ rp, const int* __restrict__ sums, int* __restrict__ cur,
                         unsigned long long* __restrict__ pk, float* __restrict__ degv) {
  __shared__ int sbase;
  int tid = threadIdx.x;
  int cid = blockIdx.x >> 3;  // 256-thread block sits inside one 2048 chunk
  if (tid == 0) {
    int b = 0;
    for (int c = 0; c < cid; ++c) b += sums[c];
    sbase = b;
  }
  __syncthreads();
  int idx = blockIdx.x * 256 + tid;
  if (idx < N_NODES) {
    int vv = rp[idx] + sbase;
    rp[idx] = vv;
    cur[idx] = vv;
    float deg = 1.0f + (float)(pk[idx] & 0xFFFFFFFFFFULL) * 5.9604644775390625e-08f;  // 2^-24
    degv[idx] = rsqrtf(deg);
    pk[idx] = 0ULL;
  }
  if (blockIdx.x == 0 && tid == 0) rp[N_NODES] = NE;
}

// pairs[p] = {src, bits(norm_w)}: ONE 8B scattered store per edge.
__global__ void k_place(const int* __restrict__ src, const int* __restrict__ dst,
                        const float* __restrict__ ew, const float* __restrict__ dinv,
                        int* __restrict__ cur, int2* __restrict__ pairs) {
  int e = blockIdx.x * 256 + threadIdx.x;
  if (e < NE) {
    int s = src[e], d = dst[e];
    float w = ew[e];
    int p = atomicAdd(&cur[d], 1);
    pairs[p] = make_int2(s, __float_as_int(dinv[s] * w * dinv[d]));
  }
}

// ---------------- GCN propagation: one wave per node, lane = feature ----------------

__global__ void k_prop(const float* __restrict__ hin, const int* __restrict__ rp,
                       const int2* __restrict__ pairs, const float* __restrict__ dinv,
                       const float* __restrict__ bias, float* __restrict__ hout,
                       int mode /*0=relu, 1=tanh*/) {
  int node = __builtin_amdgcn_readfirstlane(blockIdx.x * 4 + (threadIdx.x >> 6));
  int f = threadIdx.x & 63;
  float di = dinv[node];
  float acc = hin[(size_t)node * 64 + f] * di * di + bias[f];  // self loop: norm = dinv^2
  int e0 = rp[node], e1 = rp[node + 1];
  float a0 = 0.f, a1 = 0.f, a2 = 0.f, a3 = 0.f;
  int j = e0;
  for (; j + 4 <= e1; j += 4) {
    int2 p0 = pairs[j], p1 = pairs[j + 1], p2 = pairs[j + 2], p3 = pairs[j + 3];
    a0 = fmaf(hin[(size_t)p0.x * 64 + f], __int_as_float(p0.y), a0);
    a1 = fmaf(hin[(size_t)p1.x * 64 + f], __int_as_float(p1.y), a1);
    a2 = fmaf(hin[(size_t)p2.x * 64 + f], __int_as_float(p2.y), a2);
    a3 = fmaf(hin[(size_t)p3.x * 64 + f], __int_as_float(p3.y), a3);
  }
  for (; j < e1; ++j) {
    int2 p = pairs[j];
    acc = fmaf(hin[(size_t)p.x * 64 + f], __int_as_float(p.y), acc);
  }
  acc += (a0 + a1) + (a2 + a3);
  hout[(size_t)node * 64 + f] = (mode == 0) ? fmaxf(acc, 0.f) : tanh_f(acc);
}

// ---------------- dense matmuls ----------------

// xw1 = x @ W1 : [N,128]@[128,64]
__global__ void k_xw1(const float* __restrict__ x, const float* __restrict__ W1, float* __restrict__ o) {
  __shared__ float sW[128 * 64];   // 32 KB
  __shared__ float sx[32 * 128];   // 16 KB
  int tid = threadIdx.x;
  int row0 = blockIdx.x * 32;
  for (int i = tid; i < 128 * 64; i += 256) sW[i] = W1[i];
  for (int i = tid; i < 32 * 128; i += 256) {
    int r = i >> 7, c = i & 127;
    sx[i] = x[(size_t)(row0 + r) * 128 + c];
  }
  __syncthreads();
  int f = tid & 63, w = tid >> 6;
  float acc[8];
#pragma unroll
  for (int m = 0; m < 8; ++m) acc[m] = 0.f;
  for (int k = 0; k < 128; ++k) {
    float wv = sW[k * 64 + f];
#pragma unroll
    for (int m = 0; m < 8; ++m)
      acc[m] = fmaf(sx[(w * 8 + m) * 128 + k], wv, acc[m]);
  }
#pragma unroll
  for (int m = 0; m < 8; ++m)
    o[(size_t)(row0 + w * 8 + m) * 64 + f] = acc[m];
}

// a = a @ W2 in place : [N,64]@[64,64] (rows staged to LDS first, so in-place is safe)
__global__ void k_mm64(float* __restrict__ a, const float* __restrict__ W2) {
  __shared__ float sW[64 * 64];   // 16 KB
  __shared__ float sx[32 * 64];   // 8 KB
  int tid = threadIdx.x;
  int row0 = blockIdx.x * 32;
  for (int i = tid; i < 64 * 64; i += 256) sW[i] = W2[i];
  for (int i = tid; i < 32 * 64; i += 256) {
    int r = i >> 6, c = i & 63;
    sx[i] = a[(size_t)(row0 + r) * 64 + c];
  }
  __syncthreads();
  int f = tid & 63, w = tid >> 6;
  float acc[8];
#pragma unroll
  for (int m = 0; m < 8; ++m) acc[m] = 0.f;
  for (int k = 0; k < 64; ++k) {
    float wv = sW[k * 64 + f];
#pragma unroll
    for (int m = 0; m < 8; ++m)
      acc[m] = fmaf(sx[(w * 8 + m) * 64 + k], wv, acc[m]);
  }
#pragma unroll
  for (int m = 0; m < 8; ++m)
    a[(size_t)(row0 + w * 8 + m) * 64 + f] = acc[m];
}

// ---------------- one-time weight prepack ----------------
// Pih/Phh[k][f*4+g] = W[(g*64+f)][k] (g<3; slot 3 = pad). Moves the gate-interleave
// transpose OUT of k_gru: staging becomes a straight coalesced, conflict-free copy.
__global__ void k_prep(const float* __restrict__ Wih, const float* __restrict__ Whh,
                       const float* __restrict__ Wlin, float* __restrict__ Pih,
                       float* __restrict__ Phh, float* __restrict__ WlinT) {
  int i = blockIdx.x * 256 + threadIdx.x;   // i < 16384
  int k = i >> 8, c = i & 255, f = c >> 2, g = c & 3;
  float vi = 0.f, vh = 0.f;
  if (g < 3) {
    vi = Wih[(size_t)(g * 64 + f) * 64 + k];
    vh = Whh[(size_t)(g * 64 + f) * 64 + k];
  }
  Pih[i] = vi;
  Phh[i] = vh;
  if (i < 2048) {
    int kk = i >> 5, j = i & 31;
    WlinT[i] = Wlin[(size_t)j * 64 + kk];
  }
}

// ---------------- fused GRU step + output linear ----------------
// 256 threads = 4 waves, 8 nodes/wave, 32 nodes/block (100000 = 32*3125 exactly).
// Staging is a linear float4 copy of pre-packed weights: SQ_LDS_BANK_CONFLICT = 0 (verified).
// LAUNCH BOUNDS: the gfx950 allocator gives the arch half of the unified VGPR/AGPR
// budget -> arch regs = cap/2. Live set ~84 regs, so cap must be >=168:
//   (256,5) -> 48 regs + 1.24 GB spill; (256,4) -> 64 regs + 0.92 GB spill;
//   (256,3) -> 84 regs, no spill (verified round-0). DO NOT RAISE THE MIN-WAVES ARG.
__global__ __launch_bounds__(256, 3) void k_gru(
    const float* __restrict__ gt, float* __restrict__ h,
    const float* __restrict__ Pih, const float* __restrict__ Phh,
    const float* __restrict__ bih, const float* __restrict__ bhh,
    const float* __restrict__ WlinT, const float* __restrict__ blin,
    float* __restrict__ outt, int first) {
  __shared__ float sWi[8 * 256];    // 8 KB (k-tile of packed Wih)
  __shared__ float sWh[8 * 256];    // 8 KB
  __shared__ float sx[32 * 64];     // 8 KB
  __shared__ float sh[32 * 64];     // 8 KB

  int tid = threadIdx.x;
  int node0 = blockIdx.x * 32;

  {
    const float4* gx = (const float4*)(gt + (size_t)node0 * 64);
    float4* lx = (float4*)sx;
    float4* lh = (float4*)sh;
    lx[tid] = gx[tid];
    lx[tid + 256] = gx[tid + 256];
    if (first) {
      float4 z4 = make_float4(0.f, 0.f, 0.f, 0.f);
      lh[tid] = z4;
      lh[tid + 256] = z4;
    } else {
      const float4* gh = (const float4*)(h + (size_t)node0 * 64);
      lh[tid] = gh[tid];
      lh[tid + 256] = gh[tid + 256];
    }
  }

  int f = tid & 63;
  int w = tid >> 6;   // 0..3
  int mb = w * 8;

  float air[8], aiz[8], ain[8], ahr[8], ahz[8], ahn[8];
#pragma unroll
  for (int m = 0; m < 8; ++m) { air[m]=0.f; aiz[m]=0.f; ain[m]=0.f; ahr[m]=0.f; ahz[m]=0.f; ahn[m]=0.f; }

  for (int kt = 0; kt < 64; kt += 8) {
    __syncthreads();  // prior tile reads done (also covers initial sx/sh staging)
    {  // stage k-tile: 512 float4 per buffer, linear copy, conflict-free
      const float4* gi = (const float4*)(Pih + (size_t)kt * 256);
      const float4* gh4 = (const float4*)(Phh + (size_t)kt * 256);
      float4* li = (float4*)sWi;
      float4* lh4 = (float4*)sWh;
      li[tid] = gi[tid];
      li[tid + 256] = gi[tid + 256];
      lh4[tid] = gh4[tid];
      lh4[tid + 256] = gh4[tid + 256];
    }
    __syncthreads();
#pragma unroll
    for (int kg = 0; kg < 8; kg += 4) {
      float4 wi0 = *reinterpret_cast<const float4*>(&sWi[(kg + 0) * 256 + f * 4]);
      float4 wi1 = *reinterpret_cast<const float4*>(&sWi[(kg + 1) * 256 + f * 4]);
      float4 wi2 = *reinterpret_cast<const float4*>(&sWi[(kg + 2) * 256 + f * 4]);
      float4 wi3 = *reinterpret_cast<const float4*>(&sWi[(kg + 3) * 256 + f * 4]);
      float4 wh0 = *reinterpret_cast<const float4*>(&sWh[(kg + 0) * 256 + f * 4]);
      float4 wh1 = *reinterpret_cast<const float4*>(&sWh[(kg + 1) * 256 + f * 4]);
      float4 wh2 = *reinterpret_cast<const float4*>(&sWh[(kg + 2) * 256 + f * 4]);
      float4 wh3 = *reinterpret_cast<const float4*>(&sWh[(kg + 3) * 256 + f * 4]);
#pragma unroll
      for (int m = 0; m < 8; ++m) {
        float4 xm = *reinterpret_cast<const float4*>(&sx[(mb + m) * 64 + kt + kg]);  // broadcast
        float4 hm = *reinterpret_cast<const float4*>(&sh[(mb + m) * 64 + kt + kg]);  // broadcast
        air[m] = fmaf(xm.x, wi0.x, air[m]); aiz[m] = fmaf(xm.x, wi0.y, aiz[m]); ain[m] = fmaf(xm.x, wi0.z, ain[m]);
        ahr[m] = fmaf(hm.x, wh0.x, ahr[m]); ahz[m] = fmaf(hm.x, wh0.y, ahz[m]); ahn[m] = fmaf(hm.x, wh0.z, ahn[m]);
        air[m] = fmaf(xm.y, wi1.x, air[m]); aiz[m] = fmaf(xm.y, wi1.y, aiz[m]); ain[m] = fmaf(xm.y, wi1.z, ain[m]);
        ahr[m] = fmaf(hm.y, wh1.x, ahr[m]); ahz[m] = fmaf(hm.y, wh1.y, ahz[m]); ahn[m] = fmaf(hm.y, wh1.z, ahn[m]);
        air[m] = fmaf(xm.z, wi2.x, air[m]); aiz[m] = fmaf(xm.z, wi2.y, aiz[m]); ain[m] = fmaf(xm.z, wi2.z, ain[m]);
        ahr[m] = fmaf(hm.z, wh2.x, ahr[m]); ahz[m] = fmaf(hm.z, wh2.y, ahz[m]); ahn[m] = fmaf(hm.z, wh2.z, ahn[m]);
        air[m] = fmaf(xm.w, wi3.x, air[m]); aiz[m] = fmaf(xm.w, wi3.y, aiz[m]); ain[m] = fmaf(xm.w, wi3.z, ain[m]);
        ahr[m] = fmaf(hm.w, wh3.x, ahr[m]); ahz[m] = fmaf(hm.w, wh3.y, ahz[m]); ahn[m] = fmaf(hm.w, wh3.z, ahn[m]);
      }
    }
  }

  float bir = bih[f], biz = bih[64 + f], bin = bih[128 + f];
  float bhr = bhh[f], bhz = bhh[64 + f], bhn = bhh[128 + f];

  float hnew[8];
#pragma unroll
  for (int m = 0; m < 8; ++m) {
    float r = sigmoid_f(air[m] + bir + ahr[m] + bhr);
    float z = sigmoid_f(aiz[m] + biz + ahz[m] + bhz);
    float nn = tanh_f(ain[m] + bin + r * (ahn[m] + bhn));
    float hold = sh[(mb + m) * 64 + f];  // own-wave row, safe
    hnew[m] = (1.f - z) * nn + z * hold;
  }
#pragma unroll
  for (int m = 0; m < 8; ++m) {
    sh[(mb + m) * 64 + f] = hnew[m];  // own-wave rows only; no cross-wave hazard
    h[(size_t)(node0 + mb + m) * 64 + f] = hnew[m];
  }

  __syncthreads();  // all waves done reading sWi before reuse for WlinT
  for (int i = tid; i < 2048; i += 256) sWi[i] = WlinT[i];
  __syncthreads();

  int j = f & 31, hi = f >> 5;
  float o0 = blin[j], o1 = o0, o2 = o0, o3 = o0;
  for (int k = 0; k < 64; ++k) {
    float wv = sWi[k * 32 + j];
    o0 = fmaf(sh[(mb + 0 + hi) * 64 + k], wv, o0);
    o1 = fmaf(sh[(mb + 2 + hi) * 64 + k], wv, o1);
    o2 = fmaf(sh[(mb + 4 + hi) * 64 + k], wv, o2);
    o3 = fmaf(sh[(mb + 6 + hi) * 64 + k], wv, o3);
  }
  outt[(size_t)(node0 + mb + 0 + hi) * 32 + j] = o0;
  outt[(size_t)(node0 + mb + 2 + hi) * 32 + j] = o1;
  outt[(size_t)(node0 + mb + 4 + hi) * 32 + j] = o2;
  outt[(size_t)(node0 + mb + 6 + hi) * 32 + j] = o3;
}

// ---------------- host launch ----------------

extern "C" void kernel_launch(void* const* d_in, const int* in_sizes, int n_in,
                              void* d_out, int out_size, void* d_ws, size_t ws_size,
                              hipStream_t stream) {
  const float* x    = (const float*)d_in[0];
  const int*   eis  = (const int*)d_in[1];
  const float* ews  = (const float*)d_in[2];
  const float* W1   = (const float*)d_in[3];
  const float* b1   = (const float*)d_in[4];
  const float* W2   = (const float*)d_in[5];
  const float* b2   = (const float*)d_in[6];
  const float* Wih  = (const float*)d_in[7];
  const float* Whh  = (const float*)d_in[8];
  const float* bih  = (const float*)d_in[9];
  const float* bhh  = (const float*)d_in[10];
  const float* Wlin = (const float*)d_in[11];
  const float* blin = (const float*)d_in[12];
  float* out = (float*)d_out;

  char* ws = (char*)d_ws;
  size_t off = 0;
  auto alloc = [&](size_t bytes) { char* p = ws + off; off += (bytes + 255) & ~size_t(255); return p; };
  float* xw1  = (float*)alloc((size_t)N_NODES * 64 * 4);
  float* bufA = (float*)alloc((size_t)N_NODES * 64 * 4);  // h1, then h2 in place
  float* bufB = (float*)alloc((size_t)N_NODES * 64 * 4);  // tanh(embed_t)
  float* hst  = (float*)alloc((size_t)N_NODES * 64 * 4);  // GRU hidden state
  float* degv = (float*)alloc((size_t)N_NODES * 4);       // dinv
  unsigned long long* pk = (unsigned long long*)alloc((size_t)N_NODES * 8);
  int*   rp   = (int*)alloc((size_t)(N_NODES + 1) * 4);
  int*   cur  = (int*)alloc((size_t)(N_NODES + 1) * 4);
  int*   sums = (int*)alloc(64 * 4);
  int2*  pairs = (int2*)alloc((size_t)NE * 8);
  float* Pih  = (float*)alloc(64 * 256 * 4);
  float* Phh  = (float*)alloc(64 * 256 * 4);
  float* WlinT = (float*)alloc(64 * 32 * 4);
  if (ws_size < off) return;  // workspace too small: fail loudly in validation

  const int GB_N   = (N_NODES + 255) / 256;   // 391
  const int GB_E   = (NE + 255) / 256;        // 6250
  const int GB_SC  = (N_NODES + 2047) / 2048; // 49
  const int GB_MM  = N_NODES / 32;            // 3125
  const int GB_PR  = N_NODES / 4;             // 25000
  const int GB_GRU = N_NODES / 32;            // 3125

  k_prep<<<64, 256, 0, stream>>>(Wih, Whh, Wlin, Pih, Phh, WlinT);
  k_xw1<<<GB_MM, 256, 0, stream>>>(x, W1, xw1);
  k_init<<<GB_N, 256, 0, stream>>>(pk);   // once; k_scan_c re-zeros pk each snapshot

  for (int t = 0; t < T_STEPS; ++t) {
    const int* srcp = eis + (size_t)t * 2 * NE;
    const int* dstp = srcp + NE;
    const float* ewp = ews + (size_t)t * NE;

    k_hist<<<GB_E, 256, 0, stream>>>(dstp, ewp, pk);
    k_scan_a<<<GB_SC, 256, 0, stream>>>(pk, rp, sums);
    k_scan_c<<<GB_N, 256, 0, stream>>>(rp, sums, cur, pk, degv);
    k_place<<<GB_E, 256, 0, stream>>>(srcp, dstp, ewp, degv, cur, pairs);

    // layer 1: relu(prop(xw1) + b1) -> bufA
    k_prop<<<GB_PR, 256, 0, stream>>>(xw1, rp, pairs, degv, b1, bufA, 0);
    // h2 = h1 @ W2 (in place)
    k_mm64<<<GB_MM, 256, 0, stream>>>(bufA, W2);
    // layer 2 + GRU input activation: tanh(prop(h2) + b2) -> bufB
    k_prop<<<GB_PR, 256, 0, stream>>>(bufA, rp, pairs, degv, b2, bufB, 1);
    // GRU step + fused output linear
    k_gru<<<GB_GRU, 256, 0, stream>>>(bufB, hst, Pih, Phh, bih, bhh, WlinT, blin,
                                      out + (size_t)t * N_NODES * 32, t == 0 ? 1 : 0);
  }
}